// Round 21
// baseline (184.268 us; speedup 1.0000x reference)
//
#include <hip/hip_runtime.h>

// Correlation (FlowNet-style), kernel=1, stride=1, md=pad=4.
// B=8, C=128, H=W=192 -> out [8, 81, 192, 192] fp32.
//
// Round-21: R18 base (151 us/dispatch) with a shorter critical path:
//  (a) single pk staging set, R11's proven dbuf loop (deep prefetch was
//      measured neutral in R17; -12 VGPR -> ~124 total regs, targets the
//      128-reg 4-waves/SIMD boundary).
//  (b) epilogue: direct predicated band stores (no LDS out-tile, 2 fewer
//      barriers, ~2.6K fewer LDS ops/block). Valid lanes of a given
//      (dy,dx,r) form a full 16-px 64-B row -> coalesced (R12-validated).
//  (c) everything else R18-verbatim: xbk-fastest XCD swizzle (FETCH
//      505->158 MB win), [rho16][j24][cp16] staging w/ float4 loads,
//      contiguous-1KB frag reads, acc[9][2], 4-chunk dbuf K-loop.

#define NT 512

typedef __fp16 f16x8 __attribute__((ext_vector_type(8)));
typedef __fp16 p2 __attribute__((ext_vector_type(2)));
typedef float f32x4 __attribute__((ext_vector_type(4)));

union PK { p2 p; unsigned u; };
union FragA { f16x8 v; p2 p[4]; };

static __device__ __forceinline__ unsigned pku(float a, float b) {
  PK z; z.p = __builtin_amdgcn_cvt_pkrtz(a, b); return z.u;
}

__global__ __launch_bounds__(NT, 4)
void corr_kernel(const float* __restrict__ x1g, const float* __restrict__ x2g,
                 float* __restrict__ outg) {
  constexpr int Cc = 128, Hh = 192, Ww = 192;
  constexpr int HW = Hh * Ww;
  constexpr int ROWU = 384;   // uints per rho row (j 0..23 x 16 cp)
  constexpr int BUFU = 6400;  // 16*384 + 256 pad for jt1 overread

  __shared__ __align__(16) unsigned sm[2 * BUFU];  // 51.2 KB

  // XCD-chunked swizzle: 2304 = 8 XCDs x 288; xbk fastest (R18's win).
  const int bid = blockIdx.x;
  const int wid = (bid & 7) * 288 + (bid >> 3);
  const int xbk = wid % 12;
  const int t2 = wid / 12;
  const int yt = t2 % 24;
  const int b = t2 / 24;
  const int y0 = yt * 8, x0 = xbk * 16;

  const int tid = (int)threadIdx.x;
  const int wy = tid >> 6;      // wave = y row
  const int lane = tid & 63;
  const int lr = lane & 15;     // A row p / B col n
  const int lq = lane >> 4;     // k-block

  // ---- A fragments: x1[c][y0+wy][x0+lr], c = kc*32 + lq*8 + e ----
  FragA af[4];
  {
    const float* pA = x1g + (((size_t)b * Cc) * Hh + (y0 + wy)) * Ww + x0 + lr;
#pragma unroll
    for (int kc = 0; kc < 4; ++kc)
#pragma unroll
      for (int r = 0; r < 4; ++r) {
        const int c0 = kc * 32 + lq * 8 + 2 * r;
        af[kc].p[r] = __builtin_amdgcn_cvt_pkrtz(pA[(size_t)c0 * HW],
                                                 pA[(size_t)(c0 + 1) * HW]);
      }
  }

  // ---- staging slots (R11 mapping): s -> jf = s%6, cp = (s/6)&15, rho ----
  const float* bsrc[3];
  int loff[3];
  bool ok[3];
#pragma unroll
  for (int k = 0; k < 3; ++k) {
    const int s = tid + k * NT;
    const int jf = s % 6;
    const int t = s / 6;
    const int cp = t & 15;
    const int rho = t >> 4;          // 0..15
    const int grow = y0 - 4 + rho;
    const int gcol = x0 - 4 + 4 * jf;
    ok[k] = (grow >= 0) && (grow < Hh) && (gcol >= 0) && (gcol <= Ww - 4);
    bsrc[k] = x2g + ((size_t)(b * Cc + 2 * cp) * Hh + (ok[k] ? grow : 0)) * Ww +
              (ok[k] ? gcol : 0);
    loff[k] = rho * ROWU + jf * 64 + cp;  // +16*kk per column j = 4jf+kk
  }

  unsigned pk[3][4];
  auto bload = [&](int kc) {
#pragma unroll
    for (int k = 0; k < 3; ++k) {
      float4 v0 = make_float4(0.f, 0.f, 0.f, 0.f), v1 = v0;
      if (ok[k]) {
        const float* p = bsrc[k] + (size_t)(kc * 32) * HW;
        v0 = *(const float4*)p;         // channel 2cp, cols j..j+3
        v1 = *(const float4*)(p + HW);  // channel 2cp+1
      }
      pk[k][0] = pku(v0.x, v1.x);
      pk[k][1] = pku(v0.y, v1.y);
      pk[k][2] = pku(v0.z, v1.z);
      pk[k][3] = pku(v0.w, v1.w);
    }
  };
  auto bwrite = [&](int buf) {
    unsigned* d = sm + buf * BUFU;
#pragma unroll
    for (int k = 0; k < 3; ++k)
#pragma unroll
      for (int kk = 0; kk < 4; ++kk)
        d[loff[k] + kk * 16] = pk[k][kk];
  };

  f32x4 acc[9][2];
#pragma unroll
  for (int dy = 0; dy < 9; ++dy)
#pragma unroll
    for (int jt = 0; jt < 2; ++jt)
      acc[dy][jt] = (f32x4){0.f, 0.f, 0.f, 0.f};

  bload(0);
  bwrite(0);
  bload(1);

  const int rb = lr * 16 + lq * 4;  // uints; wave covers contiguous 1 KB

#pragma unroll
  for (int kc = 0; kc < 4; ++kc) {
    __syncthreads();                       // buf[kc&1] (chunk kc) ready
    if (kc + 1 < 4) bwrite((kc + 1) & 1);  // publish chunk kc+1
    if (kc + 2 < 4) bload(kc + 2);         // issue chunk kc+2 loads
    const unsigned* base = sm + (kc & 1) * BUFU;
#pragma unroll
    for (int dy = 0; dy < 9; ++dy) {
      const unsigned* rp = base + (wy + dy) * ROWU + rb;
      const f16x8 b0 = *(const f16x8*)(rp);        // j = lr
      const f16x8 b1 = *(const f16x8*)(rp + 256);  // j = 16+lr (lr>=8: pad)
      acc[dy][0] = __builtin_amdgcn_mfma_f32_16x16x32_f16(af[kc].v, b0,
                                                          acc[dy][0], 0, 0, 0);
      acc[dy][1] = __builtin_amdgcn_mfma_f32_16x16x32_f16(af[kc].v, b1,
                                                          acc[dy][1], 0, 0, 0);
    }
  }

  // ---- epilogue: direct predicated band stores (no LDS, no barriers) ----
  // D[row p = 4lq+r][col n = jt*16+lr]; dx = n - p; valid lanes for a given
  // (dy, dx) cover all 16 px -> 64-B rows, write-combined in L2.
  const float invc = 1.0f / 128.0f;
  const size_t outb = (((size_t)b * 81) * Hh + (y0 + wy)) * Ww + x0;
#pragma unroll
  for (int dy = 0; dy < 9; ++dy) {
    const size_t db = outb + (size_t)(dy * 9) * HW;
#pragma unroll
    for (int r = 0; r < 4; ++r) {
      const int p = 4 * lq + r;
      const int dx0 = lr - p;        // jt0 col
      const int dx1 = 16 + lr - p;   // jt1 col
      if (dx0 >= 0 && dx0 <= 8)
        outg[db + (size_t)dx0 * HW + p] = acc[dy][0][r] * invc;
      if (dx1 <= 8)
        outg[db + (size_t)dx1 * HW + p] = acc[dy][1][r] * invc;
    }
  }
}

extern "C" void kernel_launch(void* const* d_in, const int* in_sizes, int n_in,
                              void* d_out, int out_size, void* d_ws, size_t ws_size,
                              hipStream_t stream) {
  const float* x1 = (const float*)d_in[0];
  const float* x2 = (const float*)d_in[1];
  float* out = (float*)d_out;
  // grid: 8 b x 24 y-strips x 12 x-tiles = 2304 blocks (divisible by 8 XCDs)
  corr_kernel<<<dim3(2304), dim3(NT), 0, stream>>>(x1, x2, out);
}

// Round 22
// 124.259 us; speedup vs baseline: 1.4829x; 1.4829x over previous
//
#include <hip/hip_runtime.h>

// Correlation (FlowNet-style), kernel=1, stride=1, md=pad=4.
// B=8, C=128, H=W=192 -> out [8, 81, 192, 192] fp32.
//
// Round-22: R18 (best: 151 us/dispatch, bench 125.6) + counted-vmcnt
// barriers (T4). __syncthreads() lowers to "s_waitcnt vmcnt(0) lgkmcnt(0);
// s_barrier" -- draining the staged-chunk prefetch at EVERY phase barrier
// (the m97 ceiling mechanism). Replace with lgkmcnt(0)-only + raw s_barrier
// so global staging loads stay in flight across barriers; the compiler's
// automatic fine-grained vmcnt(N) before the cvt_pkrtz pack provides the
// counted wait. This explains why R17/R20 prefetch-depth changes were
// neutral: all loads drained at each barrier regardless.
//
// Everything else R18-verbatim: f16 MFMA band-GEMM, xbk-fastest XCD swizzle
// (FETCH 505->158 MB), [rho16][j24][cp16] staging (float4 loads, jf=s%6),
// contiguous-1KB frag reads, acc[9][2], deep prologue pkA/pkB, stride-132
// LDS out-tile epilogue (R21 proved direct stores regress: RMW traffic).

#define NT 512

// LDS-only barrier: orders this wave's LDS ops, leaves global loads in flight.
#define LDS_BARRIER()                                   \
  do {                                                  \
    asm volatile("s_waitcnt lgkmcnt(0)" ::: "memory");  \
    __builtin_amdgcn_s_barrier();                       \
    __builtin_amdgcn_sched_barrier(0);                  \
  } while (0)

typedef __fp16 f16x8 __attribute__((ext_vector_type(8)));
typedef __fp16 p2 __attribute__((ext_vector_type(2)));
typedef float f32x4 __attribute__((ext_vector_type(4)));

union PK { p2 p; unsigned u; };
union FragA { f16x8 v; p2 p[4]; };

static __device__ __forceinline__ unsigned pku(float a, float b) {
  PK z; z.p = __builtin_amdgcn_cvt_pkrtz(a, b); return z.u;
}

__global__ __launch_bounds__(NT, 4)
void corr_kernel(const float* __restrict__ x1g, const float* __restrict__ x2g,
                 float* __restrict__ outg) {
  constexpr int Cc = 128, Hh = 192, Ww = 192;
  constexpr int HW = Hh * Ww;
  constexpr int ROWU = 384;   // uints per rho row (j 0..23 x 16 cp)
  constexpr int BUFU = 6400;  // 16*384 + 256 pad for jt1 overread
  constexpr int PS = 132;     // epilogue plane stride (floats)

  __shared__ __align__(16) unsigned sm[2 * BUFU];  // 51.2 KB

  // XCD-chunked swizzle: 2304 = 8 XCDs x 288; xbk fastest (R18's win).
  const int bid = blockIdx.x;
  const int wid = (bid & 7) * 288 + (bid >> 3);
  const int xbk = wid % 12;
  const int t2 = wid / 12;
  const int yt = t2 % 24;
  const int b = t2 / 24;
  const int y0 = yt * 8, x0 = xbk * 16;

  const int tid = (int)threadIdx.x;
  const int wy = tid >> 6;      // wave = y row
  const int lane = tid & 63;
  const int lr = lane & 15;     // A row p / B col n
  const int lq = lane >> 4;     // k-block

  // ---- A fragments: x1[c][y0+wy][x0+lr], c = kc*32 + lq*8 + e ----
  FragA af[4];
  {
    const float* pA = x1g + (((size_t)b * Cc) * Hh + (y0 + wy)) * Ww + x0 + lr;
#pragma unroll
    for (int kc = 0; kc < 4; ++kc)
#pragma unroll
      for (int r = 0; r < 4; ++r) {
        const int c0 = kc * 32 + lq * 8 + 2 * r;
        af[kc].p[r] = __builtin_amdgcn_cvt_pkrtz(pA[(size_t)c0 * HW],
                                                 pA[(size_t)(c0 + 1) * HW]);
      }
  }

  // ---- staging slots (R11 mapping): s -> jf = s%6, cp = (s/6)&15, rho ----
  const float* bsrc[3];
  int loff[3];
  bool ok[3];
#pragma unroll
  for (int k = 0; k < 3; ++k) {
    const int s = tid + k * NT;
    const int jf = s % 6;
    const int t = s / 6;
    const int cp = t & 15;
    const int rho = t >> 4;          // 0..15
    const int grow = y0 - 4 + rho;
    const int gcol = x0 - 4 + 4 * jf;
    ok[k] = (grow >= 0) && (grow < Hh) && (gcol >= 0) && (gcol <= Ww - 4);
    bsrc[k] = x2g + ((size_t)(b * Cc + 2 * cp) * Hh + (ok[k] ? grow : 0)) * Ww +
              (ok[k] ? gcol : 0);
    loff[k] = rho * ROWU + jf * 64 + cp;  // +16*kk per column j = 4jf+kk
  }

  unsigned pkA[3][4], pkB[3][4];

  auto bload = [&](int kc, unsigned (&pk)[3][4]) {
#pragma unroll
    for (int k = 0; k < 3; ++k) {
      float4 v0 = make_float4(0.f, 0.f, 0.f, 0.f), v1 = v0;
      if (ok[k]) {
        const float* p = bsrc[k] + (size_t)(kc * 32) * HW;
        v0 = *(const float4*)p;         // channel 2cp, cols j..j+3
        v1 = *(const float4*)(p + HW);  // channel 2cp+1
      }
      pk[k][0] = pku(v0.x, v1.x);
      pk[k][1] = pku(v0.y, v1.y);
      pk[k][2] = pku(v0.z, v1.z);
      pk[k][3] = pku(v0.w, v1.w);
    }
  };
  auto bwrite = [&](int buf, unsigned (&pk)[3][4]) {
    unsigned* d = sm + buf * BUFU;   // buf MUST be 0 or 1
#pragma unroll
    for (int k = 0; k < 3; ++k)
#pragma unroll
      for (int kk = 0; kk < 4; ++kk)
        d[loff[k] + kk * 16] = pk[k][kk];
  };

  f32x4 acc[9][2];
#pragma unroll
  for (int dy = 0; dy < 9; ++dy)
#pragma unroll
    for (int jt = 0; jt < 2; ++jt)
      acc[dy][jt] = (f32x4){0.f, 0.f, 0.f, 0.f};

  // deep prologue: chunk0 published; chunk1 in pkA, chunk2 in pkB (in flight)
  bload(0, pkA);
  bwrite(0, pkA);
  bload(1, pkA);
  bload(2, pkB);

  const int rb = lr * 16 + lq * 4;  // uints; wave covers contiguous 1 KB

#pragma unroll
  for (int kc = 0; kc < 4; ++kc) {
    LDS_BARRIER();  // buf[kc&1] ready; global prefetch stays in flight
    if (kc == 0) {
      bwrite(1, pkA);   // chunk1 -> buf1
      bload(3, pkA);    // chunk3 into pkA
    } else if (kc == 1) {
      bwrite(0, pkB);   // chunk2 -> buf0 (readers of c0 done)
    } else if (kc == 2) {
      bwrite(1, pkA);   // chunk3 -> buf1 (readers of c1 done)
    }
    const unsigned* base = sm + (kc & 1) * BUFU;
#pragma unroll
    for (int dy = 0; dy < 9; ++dy) {
      const unsigned* rp = base + (wy + dy) * ROWU + rb;
      const f16x8 b0 = *(const f16x8*)(rp);        // j = lr
      const f16x8 b1 = *(const f16x8*)(rp + 256);  // j = 16+lr (lr>=8: pad)
      acc[dy][0] = __builtin_amdgcn_mfma_f32_16x16x32_f16(af[kc].v, b0,
                                                          acc[dy][0], 0, 0, 0);
      acc[dy][1] = __builtin_amdgcn_mfma_f32_16x16x32_f16(af[kc].v, b1,
                                                          acc[dy][1], 0, 0, 0);
    }
  }

  // ---- epilogue: band extract -> LDS out-tile [81][PS] -> coalesced f4 ----
  LDS_BARRIER();           // all compute LDS reads done; buffers reusable
  float* ot = (float*)sm;  // 81*132*4 = 42768 B <= 51.2 KB
  const float invc = 1.0f / 128.0f;
#pragma unroll
  for (int dy = 0; dy < 9; ++dy)
#pragma unroll
    for (int jt = 0; jt < 2; ++jt)
#pragma unroll
      for (int r = 0; r < 4; ++r) {
        const int p = 4 * lq + r;         // x pixel (C row)
        const int dx = jt * 16 + lr - p;  // C col - row
        if (dx >= 0 && dx < 9)
          ot[(dy * 9 + dx) * PS + wy * 16 + p] = acc[dy][jt][r] * invc;
      }
  LDS_BARRIER();           // out-tile visible to all waves

  for (int s = tid; s < 2592; s += NT) {  // 81 d x 8 y x 4 float4
    const int d = s >> 5;
    const int yy = (s >> 2) & 7;
    const int xf = s & 3;
    const float4 v = *(const float4*)&ot[d * PS + yy * 16 + xf * 4];
    *(float4*)&outg[(((size_t)b * 81 + d) * Hh + (y0 + yy)) * Ww + x0 + 4 * xf] = v;
  }
}

extern "C" void kernel_launch(void* const* d_in, const int* in_sizes, int n_in,
                              void* d_out, int out_size, void* d_ws, size_t ws_size,
                              hipStream_t stream) {
  const float* x1 = (const float*)d_in[0];
  const float* x2 = (const float*)d_in[1];
  float* out = (float*)d_out;
  // grid: 8 b x 24 y-strips x 12 x-tiles = 2304 blocks (divisible by 8 XCDs)
  corr_kernel<<<dim3(2304), dim3(NT), 0, stream>>>(x1, x2, out);
}